// Round 6
// baseline (356.866 us; speedup 1.0000x reference)
//
#include <hip/hip_runtime.h>

#define H 64
#define CAP 64   // padded CSR row capacity. deg ~ Poisson(12): P(>64) ~ 1e-25.

// f32 -> bf16 (RNE), returned in low 16 bits
__device__ __forceinline__ unsigned f2bf(float f) {
    unsigned u = __float_as_uint(f);
    u += 0x7fffu + ((u >> 16) & 1u);
    return u >> 16;
}
__device__ __forceinline__ float bf_lo(unsigned u) { return __uint_as_float(u << 16); }
__device__ __forceinline__ float bf_hi(unsigned u) { return __uint_as_float(u & 0xffff0000u); }

// ---------------------------------------------------------------------------
// K0: fold Wx into the four projection matrices (tiny, 1 block).
// Wf[m][i][c] = sum_h Wx[i][h] * Wm[h][c]   (i<16, c<64, m in {q,k,v,s})
// bf[m][c]   = sum_h bx[h] * Wm[h][c] + bm[c]
// ---------------------------------------------------------------------------
__global__ __launch_bounds__(256) void k_fold(
    const float* __restrict__ Wx, const float* __restrict__ bx,
    const float* __restrict__ Wq, const float* __restrict__ bq,
    const float* __restrict__ Wk, const float* __restrict__ bk,
    const float* __restrict__ Wv, const float* __restrict__ bv,
    const float* __restrict__ Ws, const float* __restrict__ bs,
    float* __restrict__ Wf, float* __restrict__ bf)
{
    const int t = threadIdx.x;
    const int c = t & 63, m = t >> 6;
    const float* W; const float* b;
    switch (m) {
        case 0:  W = Wq; b = bq; break;
        case 1:  W = Wk; b = bk; break;
        case 2:  W = Wv; b = bv; break;
        default: W = Ws; b = bs; break;
    }
    float acc[16];
#pragma unroll
    for (int i = 0; i < 16; ++i) acc[i] = 0.f;
    float bacc = b[c];
    for (int j = 0; j < 64; ++j) {
        const float wv = W[j * 64 + c];
        bacc += bx[j] * wv;
#pragma unroll
        for (int i = 0; i < 16; ++i) acc[i] += Wx[i * 64 + j] * wv;
    }
#pragma unroll
    for (int i = 0; i < 16; ++i) Wf[(m * 16 + i) * 64 + c] = acc[i];
    bf[m * 64 + c] = bacc;
}

// ---------------------------------------------------------------------------
// K1: per-node transform (folded weights, K=16) + fused direct-CSR fill.
// Outputs packed bf16: kv[n*H+c] = {lo: k, hi: v}, qs[n*H+c] = {lo: q, hi: skip}.
// ---------------------------------------------------------------------------
__global__ __launch_bounds__(256) void k_node_transform(
    const float* __restrict__ x,
    const float* __restrict__ Wf, const float* __restrict__ bf,
    unsigned* __restrict__ qs, unsigned* __restrict__ kv,
    const int* __restrict__ src, const int* __restrict__ dst,
    int* __restrict__ cursor, int2* __restrict__ csr2,
    int N, int E)
{
    __shared__ float sx[16][16];
    const int t = threadIdx.x;
    const int node0 = blockIdx.x * 16;

    // fused CSR fill (independent of node work)
    {
        const int e = blockIdx.x * 256 + t;
        if (e < E) {
            const int s = src[e];
            const int d = dst[e];
            const int pos = atomicAdd(&cursor[d], 1);
            if (pos < CAP) csr2[(size_t)d * CAP + pos] = make_int2(e, s);
        }
    }

    {
        const int nl = t >> 4, i = t & 15;
        const int n = node0 + nl;
        sx[nl][i] = (n < N) ? x[n * 16 + i] : 0.f;
    }
    __syncthreads();

    const int c  = t & 63;
    const int ng = t >> 6;

    float aq[4], ak[4], av[4], as_[4];
#pragma unroll
    for (int m = 0; m < 4; ++m) {
        aq[m] = bf[0 * 64 + c];
        ak[m] = bf[1 * 64 + c];
        av[m] = bf[2 * 64 + c];
        as_[m] = bf[3 * 64 + c];
    }

#pragma unroll
    for (int i = 0; i < 16; ++i) {
        const float wq = Wf[(0 * 16 + i) * 64 + c];
        const float wk = Wf[(1 * 16 + i) * 64 + c];
        const float wv = Wf[(2 * 16 + i) * 64 + c];
        const float ws = Wf[(3 * 16 + i) * 64 + c];
#pragma unroll
        for (int m = 0; m < 4; ++m) {
            const float xv = sx[ng * 4 + m][i];
            aq[m] += xv * wq;
            ak[m] += xv * wk;
            av[m] += xv * wv;
            as_[m] += xv * ws;
        }
    }
#pragma unroll
    for (int m = 0; m < 4; ++m) {
        const int n = node0 + ng * 4 + m;
        if (n < N) {
            qs[(size_t)n * H + c] = f2bf(aq[m]) | (f2bf(as_[m]) << 16);
            kv[(size_t)n * H + c] = f2bf(ak[m]) | (f2bf(av[m]) << 16);
        }
    }
}

// ---------------------------------------------------------------------------
// slot accumulate: one edge (16-lane group), lane holds 4 channels
// ---------------------------------------------------------------------------
__device__ __forceinline__ void slot_acc(
    bool valid, const uint4 r, const float4 A,
    const float4 w0, const float4 w1, const float4 w2, const float4 w3,
    float q0, float q1, float q2, float q3,
    float& a0, float& a1, float& a2, float& a3, float& dn)
{
    const float e0 = A.x * w0.x + A.y * w1.x + A.z * w2.x + A.w * w3.x;
    const float e1 = A.x * w0.y + A.y * w1.y + A.z * w2.y + A.w * w3.y;
    const float e2 = A.x * w0.z + A.y * w1.z + A.z * w2.z + A.w * w3.z;
    const float e3 = A.x * w0.w + A.y * w1.w + A.z * w2.w + A.w * w3.w;
    const float k0 = bf_lo(r.x), v0 = bf_hi(r.x);
    const float k1 = bf_lo(r.y), v1 = bf_hi(r.y);
    const float k2 = bf_lo(r.z), v2 = bf_hi(r.z);
    const float k3 = bf_lo(r.w), v3 = bf_hi(r.w);
    float p = q0 * (k0 + e0) + q1 * (k1 + e1)
            + q2 * (k2 + e2) + q3 * (k3 + e3);
    p += __shfl_xor(p, 1);
    p += __shfl_xor(p, 2);
    p += __shfl_xor(p, 4);
    p += __shfl_xor(p, 8);
    const float a = valid ? __expf(p * 0.125f) : 0.f;
    a0 += a * (v0 + e0);
    a1 += a * (v1 + e1);
    a2 += a * (v2 + e2);
    a3 += a * (v3 + e3);
    dn += a;
}

// in-wave MLP head: h replicated across groups; 16-lane-group shuffle dot
__device__ __forceinline__ float mlp_head(
    float h0, float h1, float h2, float h3, int c0,
    const float* __restrict__ W1, const float* __restrict__ b1,
    const float* __restrict__ W2, const float* __restrict__ b2)
{
    float part[8];
#pragma unroll
    for (int j = 0; j < 8; ++j) {
        part[j] = h0 * W1[(c0 + 0) * 8 + j] + h1 * W1[(c0 + 1) * 8 + j]
                + h2 * W1[(c0 + 2) * 8 + j] + h3 * W1[(c0 + 3) * 8 + j];
    }
#pragma unroll
    for (int j = 0; j < 8; ++j) {
        part[j] += __shfl_xor(part[j], 1);
        part[j] += __shfl_xor(part[j], 2);
        part[j] += __shfl_xor(part[j], 4);
        part[j] += __shfl_xor(part[j], 8);
    }
    float val = b2[0];
#pragma unroll
    for (int j = 0; j < 8; ++j)
        val += fmaxf(part[j] + b1[j], 0.f) * W2[j];
    return val;
}

// ---------------------------------------------------------------------------
// K2: fused alpha + aggregation + MLP head + edge-output scatter.
// TWO nodes per wave (independent gather chains overlap), no LDS, no barrier.
// 16 lanes per edge-slot, 4 slots per wave per node, unroll x2 -> 8 edges
// in flight per node, 16 total.
// ---------------------------------------------------------------------------
__global__ __launch_bounds__(256, 4) void k_node_agg(
    const int* __restrict__ degp, const int2* __restrict__ csr2,
    const unsigned* __restrict__ qs, const unsigned* __restrict__ kv,
    const float* __restrict__ ea, const float* __restrict__ We,
    const float* __restrict__ W1, const float* __restrict__ b1,
    const float* __restrict__ W2, const float* __restrict__ b2,
    float* __restrict__ out, int N)
{
    const int t = threadIdx.x;
    const int l = t & 63;
    const int w = t >> 6;
    const int grp = l >> 4;          // edge slot 0..3
    const int c0  = (l & 15) * 4;    // this lane's 4 channels
    const int nA = blockIdx.x * 8 + w;
    const int nB = nA + 4;

    const float4 w0 = *(const float4*)&We[0 * H + c0];
    const float4 w1 = *(const float4*)&We[1 * H + c0];
    const float4 w2 = *(const float4*)&We[2 * H + c0];
    const float4 w3 = *(const float4*)&We[3 * H + c0];

    // node A state
    int degA = 0; size_t baseA = 0;
    float qA0 = 0, qA1 = 0, qA2 = 0, qA3 = 0, sA0 = 0, sA1 = 0, sA2 = 0, sA3 = 0;
    if (nA < N) {
        degA = min(degp[nA], CAP);
        baseA = (size_t)nA * CAP;
        const uint4 qr = *(const uint4*)&qs[(size_t)nA * H + c0];
        qA0 = bf_lo(qr.x); sA0 = bf_hi(qr.x);
        qA1 = bf_lo(qr.y); sA1 = bf_hi(qr.y);
        qA2 = bf_lo(qr.z); sA2 = bf_hi(qr.z);
        qA3 = bf_lo(qr.w); sA3 = bf_hi(qr.w);
    }
    // node B state
    int degB = 0; size_t baseB = 0;
    float qB0 = 0, qB1 = 0, qB2 = 0, qB3 = 0, sB0 = 0, sB1 = 0, sB2 = 0, sB3 = 0;
    if (nB < N) {
        degB = min(degp[nB], CAP);
        baseB = (size_t)nB * CAP;
        const uint4 qr = *(const uint4*)&qs[(size_t)nB * H + c0];
        qB0 = bf_lo(qr.x); sB0 = bf_hi(qr.x);
        qB1 = bf_lo(qr.y); sB1 = bf_hi(qr.y);
        qB2 = bf_lo(qr.z); sB2 = bf_hi(qr.z);
        qB3 = bf_lo(qr.w); sB3 = bf_hi(qr.w);
    }

    float aA0 = 0, aA1 = 0, aA2 = 0, aA3 = 0, dA = 0;
    float aB0 = 0, aB1 = 0, aB2 = 0, aB3 = 0, dB = 0;

    const int degM = max(degA, degB);
    for (int base = 0; base < degM; base += 8) {
        const int ia = base + grp;
        const int ib = base + 4 + grp;
        const bool vAa = ia < degA, vAb = ib < degA;
        const bool vBa = ia < degB, vBb = ib < degB;
        // level 1: csr entries (4 independent loads)
        const int2 cAa = csr2[baseA + (vAa ? ia : 0)];
        const int2 cAb = csr2[baseA + (vAb ? ib : 0)];
        const int2 cBa = csr2[baseB + (vBa ? ia : 0)];
        const int2 cBb = csr2[baseB + (vBb ? ib : 0)];
        // level 2: kv rows + edge attrs (8 independent loads)
        const uint4 rAa = *(const uint4*)&kv[(size_t)cAa.y * H + c0];
        const uint4 rAb = *(const uint4*)&kv[(size_t)cAb.y * H + c0];
        const uint4 rBa = *(const uint4*)&kv[(size_t)cBa.y * H + c0];
        const uint4 rBb = *(const uint4*)&kv[(size_t)cBb.y * H + c0];
        const float4 AAa = *(const float4*)&ea[(size_t)cAa.x * 4];
        const float4 AAb = *(const float4*)&ea[(size_t)cAb.x * 4];
        const float4 ABa = *(const float4*)&ea[(size_t)cBa.x * 4];
        const float4 ABb = *(const float4*)&ea[(size_t)cBb.x * 4];

        slot_acc(vAa, rAa, AAa, w0, w1, w2, w3, qA0, qA1, qA2, qA3, aA0, aA1, aA2, aA3, dA);
        slot_acc(vAb, rAb, AAb, w0, w1, w2, w3, qA0, qA1, qA2, qA3, aA0, aA1, aA2, aA3, dA);
        slot_acc(vBa, rBa, ABa, w0, w1, w2, w3, qB0, qB1, qB2, qB3, aB0, aB1, aB2, aB3, dB);
        slot_acc(vBb, rBb, ABb, w0, w1, w2, w3, qB0, qB1, qB2, qB3, aB0, aB1, aB2, aB3, dB);
    }

    // cross-slot reduce (slots hold disjoint edges, same channels)
    aA0 += __shfl_xor(aA0, 16); aA0 += __shfl_xor(aA0, 32);
    aA1 += __shfl_xor(aA1, 16); aA1 += __shfl_xor(aA1, 32);
    aA2 += __shfl_xor(aA2, 16); aA2 += __shfl_xor(aA2, 32);
    aA3 += __shfl_xor(aA3, 16); aA3 += __shfl_xor(aA3, 32);
    dA  += __shfl_xor(dA, 16);  dA  += __shfl_xor(dA, 32);
    aB0 += __shfl_xor(aB0, 16); aB0 += __shfl_xor(aB0, 32);
    aB1 += __shfl_xor(aB1, 16); aB1 += __shfl_xor(aB1, 32);
    aB2 += __shfl_xor(aB2, 16); aB2 += __shfl_xor(aB2, 32);
    aB3 += __shfl_xor(aB3, 16); aB3 += __shfl_xor(aB3, 32);
    dB  += __shfl_xor(dB, 16);  dB  += __shfl_xor(dB, 32);

    const float invA = 1.f / (dA + 1e-16f);
    const float invB = 1.f / (dB + 1e-16f);
    const float hA0 = aA0 * invA + sA0, hA1 = aA1 * invA + sA1;
    const float hA2 = aA2 * invA + sA2, hA3 = aA3 * invA + sA3;
    const float hB0 = aB0 * invB + sB0, hB1 = aB1 * invB + sB1;
    const float hB2 = aB2 * invB + sB2, hB3 = aB3 * invB + sB3;

    const float valA = mlp_head(hA0, hA1, hA2, hA3, c0, W1, b1, W2, b2);
    const float valB = mlp_head(hB0, hB1, hB2, hB3, c0, W1, b1, W2, b2);

    // scatter per-edge output (csr2 rows are L2-hot from the loop above)
    for (int i = l; i < degA; i += 64) out[csr2[baseA + i].x] = valA;
    for (int i = l; i < degB; i += 64) out[csr2[baseB + i].x] = valB;
}

// ---------------------------------------------------------------------------
extern "C" void kernel_launch(void* const* d_in, const int* in_sizes, int n_in,
                              void* d_out, int out_size, void* d_ws, size_t ws_size,
                              hipStream_t stream)
{
    const int*   src = (const int*)d_in[0];
    const int*   dst = (const int*)d_in[1];
    const float* x   = (const float*)d_in[3];
    const float* ea  = (const float*)d_in[4];
    const float* Wx  = (const float*)d_in[5];
    const float* bx  = (const float*)d_in[6];
    const float* Wq  = (const float*)d_in[7];
    const float* bq  = (const float*)d_in[8];
    const float* Wk  = (const float*)d_in[9];
    const float* bk  = (const float*)d_in[10];
    const float* Wv  = (const float*)d_in[11];
    const float* bv  = (const float*)d_in[12];
    const float* We  = (const float*)d_in[13];
    const float* Ws  = (const float*)d_in[14];
    const float* bs  = (const float*)d_in[15];
    const float* W1  = (const float*)d_in[16];
    const float* b1  = (const float*)d_in[17];
    const float* W2  = (const float*)d_in[18];
    const float* b2  = (const float*)d_in[19];

    const int E = in_sizes[0];
    const int N = in_sizes[3] / 16;
    float* out = (float*)d_out;

    // workspace layout
    const size_t N64 = (size_t)N * H;
    unsigned* qs  = (unsigned*)d_ws;                 // N*H packed {q, skip}
    unsigned* kv  = qs + N64;                        // N*H packed {k, v}
    int2* csr2    = (int2*)(kv + N64);               // N*CAP pairs (e, src)
    int* cursor   = (int*)(csr2 + (size_t)N * CAP);  // N
    float* Wf     = (float*)(cursor + N);            // 4*16*64
    float* bf     = Wf + 4 * 16 * 64;                // 4*64

    hipMemsetAsync(cursor, 0, (size_t)N * sizeof(int), stream);

    k_fold<<<1, 256, 0, stream>>>(Wx, bx, Wq, bq, Wk, bk, Wv, bv, Ws, bs, Wf, bf);

    const int nbN16 = (N + 15) / 16;
    const int nbE   = (E + 255) / 256;
    const int grid1 = nbN16 > nbE ? nbN16 : nbE;   // covers nodes AND edges
    k_node_transform<<<grid1, 256, 0, stream>>>(
        x, Wf, bf, qs, kv, src, dst, cursor, csr2, N, E);

    k_node_agg<<<(N + 7) / 8, 256, 0, stream>>>(
        cursor, csr2, qs, kv, ea, We, W1, b1, W2, b2, out, N);
}

// Round 7
// 342.926 us; speedup vs baseline: 1.0407x; 1.0407x over previous
//
#include <hip/hip_runtime.h>

#define H 64
#define CAP 48   // padded CSR row capacity. deg ~ Poisson(12): P(>48) < 1e-9.

// f32 -> bf16 (RNE), returned in low 16 bits
__device__ __forceinline__ unsigned f2bf(float f) {
    unsigned u = __float_as_uint(f);
    u += 0x7fffu + ((u >> 16) & 1u);
    return u >> 16;
}
__device__ __forceinline__ float bf_lo(unsigned u) { return __uint_as_float(u << 16); }
__device__ __forceinline__ float bf_hi(unsigned u) { return __uint_as_float(u & 0xffff0000u); }

// ---------------------------------------------------------------------------
// K0: fold Wx into the four projection matrices (tiny, 1 block).
// Wf[m][i][c] = sum_h Wx[i][h] * Wm[h][c]   (i<16, c<64, m in {q,k,v,s})
// bf[m][c]   = sum_h bx[h] * Wm[h][c] + bm[c]
// ---------------------------------------------------------------------------
__global__ __launch_bounds__(256) void k_fold(
    const float* __restrict__ Wx, const float* __restrict__ bx,
    const float* __restrict__ Wq, const float* __restrict__ bq,
    const float* __restrict__ Wk, const float* __restrict__ bk,
    const float* __restrict__ Wv, const float* __restrict__ bv,
    const float* __restrict__ Ws, const float* __restrict__ bs,
    float* __restrict__ Wf, float* __restrict__ bf)
{
    const int t = threadIdx.x;
    const int c = t & 63, m = t >> 6;
    const float* W; const float* b;
    switch (m) {
        case 0:  W = Wq; b = bq; break;
        case 1:  W = Wk; b = bk; break;
        case 2:  W = Wv; b = bv; break;
        default: W = Ws; b = bs; break;
    }
    float acc[16];
#pragma unroll
    for (int i = 0; i < 16; ++i) acc[i] = 0.f;
    float bacc = b[c];
    for (int j = 0; j < 64; ++j) {
        const float wv = W[j * 64 + c];
        bacc += bx[j] * wv;
#pragma unroll
        for (int i = 0; i < 16; ++i) acc[i] += Wx[i * 64 + j] * wv;
    }
#pragma unroll
    for (int i = 0; i < 16; ++i) Wf[(m * 16 + i) * 64 + c] = acc[i];
    bf[m * 64 + c] = bacc;
}

// ---------------------------------------------------------------------------
// K1: per-node transform (folded weights, K=16) + fused edge-record fill.
// Outputs packed bf16: kv[n*H+c] = {lo: k, hi: v}, qs[n*H+c] = {lo: q, hi: skip}.
// Edge record: int4 {src, e, bf16x2(A0,A1), bf16x2(A2,A3)} at csr[d*CAP+pos].
// ---------------------------------------------------------------------------
__global__ __launch_bounds__(256) void k_node_transform(
    const float* __restrict__ x,
    const float* __restrict__ Wf, const float* __restrict__ bf,
    unsigned* __restrict__ qs, unsigned* __restrict__ kv,
    const int* __restrict__ src, const int* __restrict__ dst,
    const float4* __restrict__ ea4,
    int* __restrict__ cursor, int4* __restrict__ csr,
    int N, int E)
{
    __shared__ float sx[16][16];
    const int t = threadIdx.x;
    const int node0 = blockIdx.x * 16;

    // fused edge-record fill (independent of node work)
    {
        const int e = blockIdx.x * 256 + t;
        if (e < E) {
            const int s = src[e];
            const int d = dst[e];
            const float4 A = ea4[e];
            const int pos = atomicAdd(&cursor[d], 1);
            if (pos < CAP) {
                int4 ent;
                ent.x = s;
                ent.y = e;
                ent.z = (int)(f2bf(A.x) | (f2bf(A.y) << 16));
                ent.w = (int)(f2bf(A.z) | (f2bf(A.w) << 16));
                csr[(size_t)d * CAP + pos] = ent;
            }
        }
    }

    {
        const int nl = t >> 4, i = t & 15;
        const int n = node0 + nl;
        sx[nl][i] = (n < N) ? x[n * 16 + i] : 0.f;
    }
    __syncthreads();

    const int c  = t & 63;
    const int ng = t >> 6;

    float aq[4], ak[4], av[4], as_[4];
#pragma unroll
    for (int m = 0; m < 4; ++m) {
        aq[m] = bf[0 * 64 + c];
        ak[m] = bf[1 * 64 + c];
        av[m] = bf[2 * 64 + c];
        as_[m] = bf[3 * 64 + c];
    }

#pragma unroll
    for (int i = 0; i < 16; ++i) {
        const float wq = Wf[(0 * 16 + i) * 64 + c];
        const float wk = Wf[(1 * 16 + i) * 64 + c];
        const float wv = Wf[(2 * 16 + i) * 64 + c];
        const float ws = Wf[(3 * 16 + i) * 64 + c];
#pragma unroll
        for (int m = 0; m < 4; ++m) {
            const float xv = sx[ng * 4 + m][i];
            aq[m] += xv * wq;
            ak[m] += xv * wk;
            av[m] += xv * wv;
            as_[m] += xv * ws;
        }
    }
#pragma unroll
    for (int m = 0; m < 4; ++m) {
        const int n = node0 + ng * 4 + m;
        if (n < N) {
            qs[(size_t)n * H + c] = f2bf(aq[m]) | (f2bf(as_[m]) << 16);
            kv[(size_t)n * H + c] = f2bf(ak[m]) | (f2bf(av[m]) << 16);
        }
    }
}

// ---------------------------------------------------------------------------
// K2: fused alpha + aggregation + MLP head + edge-output scatter.
// ONE node per wave (4 independent waves/block, no LDS, no barrier).
// 16 lanes per edge-slot, 4 slots/wave, unroll x2 -> 8 edges in flight.
// alpha = q.k + A.r  with r = We@q (4 floats/node, 16 shuffles once);
// edge-feature output via 4-dim accumulator S = sum(a*A), folded in epilogue.
// ---------------------------------------------------------------------------
__global__ __launch_bounds__(256) void k_node_agg(
    const int* __restrict__ degp, const int4* __restrict__ csr,
    const unsigned* __restrict__ qs, const unsigned* __restrict__ kv,
    const float* __restrict__ We,
    const float* __restrict__ W1, const float* __restrict__ b1,
    const float* __restrict__ W2, const float* __restrict__ b2,
    float* __restrict__ out, int N)
{
    const int t = threadIdx.x;
    const int l = t & 63;
    const int w = t >> 6;
    const int n = blockIdx.x * 4 + w;
    if (n >= N) return;                  // wave-uniform exit, barrier-free kernel
    const int grp = l >> 4;              // edge slot 0..3
    const int c0  = (l & 15) * 4;        // this lane's 4 channels (same in all slots)

    const int deg = min(degp[n], CAP);
    const size_t nbase = (size_t)n * CAP;

    const float4 w0 = *(const float4*)&We[0 * H + c0];
    const float4 w1 = *(const float4*)&We[1 * H + c0];
    const float4 w2 = *(const float4*)&We[2 * H + c0];
    const float4 w3 = *(const float4*)&We[3 * H + c0];
    const uint4 qr = *(const uint4*)&qs[(size_t)n * H + c0];
    const float q0 = bf_lo(qr.x), sk0 = bf_hi(qr.x);
    const float q1 = bf_lo(qr.y), sk1 = bf_hi(qr.y);
    const float q2 = bf_lo(qr.z), sk2 = bf_hi(qr.z);
    const float q3 = bf_lo(qr.w), sk3 = bf_hi(qr.w);

    // r_j = sum_c We[j][c] q_c  (16-group butterfly; q replicated across slots)
    float r0 = w0.x * q0 + w0.y * q1 + w0.z * q2 + w0.w * q3;
    float r1 = w1.x * q0 + w1.y * q1 + w1.z * q2 + w1.w * q3;
    float r2 = w2.x * q0 + w2.y * q1 + w2.z * q2 + w2.w * q3;
    float r3 = w3.x * q0 + w3.y * q1 + w3.z * q2 + w3.w * q3;
#pragma unroll
    for (int d = 1; d < 16; d <<= 1) {
        r0 += __shfl_xor(r0, d);
        r1 += __shfl_xor(r1, d);
        r2 += __shfl_xor(r2, d);
        r3 += __shfl_xor(r3, d);
    }

    float acc0 = 0, acc1 = 0, acc2 = 0, acc3 = 0, den = 0;
    float S0 = 0, S1 = 0, S2 = 0, S3 = 0;

    for (int base = 0; base < deg; base += 8) {
        const int ia = base + grp;
        const int ib = base + 4 + grp;
        const bool va = ia < deg;
        const bool vb = ib < deg;
        const int4 Ea = csr[nbase + (va ? ia : 0)];
        const int4 Eb = csr[nbase + (vb ? ib : 0)];
        const uint4 ra = *(const uint4*)&kv[(size_t)Ea.x * H + c0];
        const uint4 rb = *(const uint4*)&kv[(size_t)Eb.x * H + c0];

        // slot a
        {
            const float A0 = bf_lo((unsigned)Ea.z), A1 = bf_hi((unsigned)Ea.z);
            const float A2 = bf_lo((unsigned)Ea.w), A3 = bf_hi((unsigned)Ea.w);
            const float k0 = bf_lo(ra.x), v0 = bf_hi(ra.x);
            const float k1 = bf_lo(ra.y), v1 = bf_hi(ra.y);
            const float k2 = bf_lo(ra.z), v2 = bf_hi(ra.z);
            const float k3 = bf_lo(ra.w), v3 = bf_hi(ra.w);
            float p = q0 * k0 + q1 * k1 + q2 * k2 + q3 * k3;
            p += __shfl_xor(p, 1);
            p += __shfl_xor(p, 2);
            p += __shfl_xor(p, 4);
            p += __shfl_xor(p, 8);
            p += A0 * r0 + A1 * r1 + A2 * r2 + A3 * r3;
            const float a = va ? __expf(p * 0.125f) : 0.f;
            acc0 += a * v0; acc1 += a * v1; acc2 += a * v2; acc3 += a * v3;
            S0 += a * A0; S1 += a * A1; S2 += a * A2; S3 += a * A3;
            den += a;
        }
        // slot b
        {
            const float A0 = bf_lo((unsigned)Eb.z), A1 = bf_hi((unsigned)Eb.z);
            const float A2 = bf_lo((unsigned)Eb.w), A3 = bf_hi((unsigned)Eb.w);
            const float k0 = bf_lo(rb.x), v0 = bf_hi(rb.x);
            const float k1 = bf_lo(rb.y), v1 = bf_hi(rb.y);
            const float k2 = bf_lo(rb.z), v2 = bf_hi(rb.z);
            const float k3 = bf_lo(rb.w), v3 = bf_hi(rb.w);
            float p = q0 * k0 + q1 * k1 + q2 * k2 + q3 * k3;
            p += __shfl_xor(p, 1);
            p += __shfl_xor(p, 2);
            p += __shfl_xor(p, 4);
            p += __shfl_xor(p, 8);
            p += A0 * r0 + A1 * r1 + A2 * r2 + A3 * r3;
            const float a = vb ? __expf(p * 0.125f) : 0.f;
            acc0 += a * v0; acc1 += a * v1; acc2 += a * v2; acc3 += a * v3;
            S0 += a * A0; S1 += a * A1; S2 += a * A2; S3 += a * A3;
            den += a;
        }
    }

    // cross-slot reduce (slots hold disjoint edges, same channels)
#pragma unroll
    for (int d = 16; d < 64; d <<= 1) {
        acc0 += __shfl_xor(acc0, d);
        acc1 += __shfl_xor(acc1, d);
        acc2 += __shfl_xor(acc2, d);
        acc3 += __shfl_xor(acc3, d);
        S0 += __shfl_xor(S0, d);
        S1 += __shfl_xor(S1, d);
        S2 += __shfl_xor(S2, d);
        S3 += __shfl_xor(S3, d);
        den += __shfl_xor(den, d);
    }

    const float inv = 1.f / (den + 1e-16f);
    const float h0 = (acc0 + S0 * w0.x + S1 * w1.x + S2 * w2.x + S3 * w3.x) * inv + sk0;
    const float h1 = (acc1 + S0 * w0.y + S1 * w1.y + S2 * w2.y + S3 * w3.y) * inv + sk1;
    const float h2 = (acc2 + S0 * w0.z + S1 * w1.z + S2 * w2.z + S3 * w3.z) * inv + sk2;
    const float h3 = (acc3 + S0 * w0.w + S1 * w1.w + S2 * w2.w + S3 * w3.w) * inv + sk3;

    // in-wave MLP head (h replicated across slots; 16-group shuffle dot)
    float part[8];
#pragma unroll
    for (int j = 0; j < 8; ++j) {
        part[j] = h0 * W1[(c0 + 0) * 8 + j] + h1 * W1[(c0 + 1) * 8 + j]
                + h2 * W1[(c0 + 2) * 8 + j] + h3 * W1[(c0 + 3) * 8 + j];
    }
#pragma unroll
    for (int j = 0; j < 8; ++j) {
        part[j] += __shfl_xor(part[j], 1);
        part[j] += __shfl_xor(part[j], 2);
        part[j] += __shfl_xor(part[j], 4);
        part[j] += __shfl_xor(part[j], 8);
    }
    float val = b2[0];
#pragma unroll
    for (int j = 0; j < 8; ++j)
        val += fmaxf(part[j] + b1[j], 0.f) * W2[j];

    // scatter per-edge output (csr rows are L2-hot from the loop above)
    for (int i = l; i < deg; i += 64)
        out[csr[nbase + i].y] = val;
}

// ---------------------------------------------------------------------------
extern "C" void kernel_launch(void* const* d_in, const int* in_sizes, int n_in,
                              void* d_out, int out_size, void* d_ws, size_t ws_size,
                              hipStream_t stream)
{
    const int*   src = (const int*)d_in[0];
    const int*   dst = (const int*)d_in[1];
    const float* x   = (const float*)d_in[3];
    const float* ea  = (const float*)d_in[4];
    const float* Wx  = (const float*)d_in[5];
    const float* bx  = (const float*)d_in[6];
    const float* Wq  = (const float*)d_in[7];
    const float* bq  = (const float*)d_in[8];
    const float* Wk  = (const float*)d_in[9];
    const float* bk  = (const float*)d_in[10];
    const float* Wv  = (const float*)d_in[11];
    const float* bv  = (const float*)d_in[12];
    const float* We  = (const float*)d_in[13];
    const float* Ws  = (const float*)d_in[14];
    const float* bs  = (const float*)d_in[15];
    const float* W1  = (const float*)d_in[16];
    const float* b1  = (const float*)d_in[17];
    const float* W2  = (const float*)d_in[18];
    const float* b2  = (const float*)d_in[19];

    const int E = in_sizes[0];
    const int N = in_sizes[3] / 16;
    float* out = (float*)d_out;

    // workspace layout (~128 MB)
    const size_t N64 = (size_t)N * H;
    unsigned* qs  = (unsigned*)d_ws;                 // N*H packed {q, skip}
    unsigned* kv  = qs + N64;                        // N*H packed {k, v}
    int4* csr     = (int4*)(kv + N64);               // N*CAP records
    int* cursor   = (int*)(csr + (size_t)N * CAP);   // N
    float* Wf     = (float*)(cursor + N);            // 4*16*64
    float* bfp    = Wf + 4 * 16 * 64;                // 4*64

    hipMemsetAsync(cursor, 0, (size_t)N * sizeof(int), stream);

    k_fold<<<1, 256, 0, stream>>>(Wx, bx, Wq, bq, Wk, bk, Wv, bv, Ws, bs, Wf, bfp);

    const int nbN16 = (N + 15) / 16;
    const int nbE   = (E + 255) / 256;
    const int grid1 = nbN16 > nbE ? nbN16 : nbE;   // covers nodes AND edges
    k_node_transform<<<grid1, 256, 0, stream>>>(
        x, Wf, bfp, qs, kv, src, dst, (const float4*)ea, cursor, csr, N, E);

    k_node_agg<<<(N + 3) / 4, 256, 0, stream>>>(
        cursor, csr, qs, kv, We, W1, b1, W2, b2, out, N);
}

// Round 8
// 299.487 us; speedup vs baseline: 1.1916x; 1.1450x over previous
//
#include <hip/hip_runtime.h>

#define H 64
#define CAP 48   // padded CSR row capacity. deg ~ Poisson(12): P(>48) < 1e-9.

// constant-block offsets (floats)
#define OFF_M   0     // M[i][j] 16x16 : i*16+j
#define OFF_U   256   // u[16]
#define OFF_W   272   // w[16]
#define OFF_C   288   // scalar
#define OFF_R   292   // R[j][i] 4x16 : j*16+i
#define OFF_R0  356   // r0[4]
#define OFF_PV  360   // Pv[i][j] 16x8 : i*8+j
#define OFF_PE  488   // Pe[m][j] 4x8
#define OFF_PS  520   // Ps[i][j] 16x8
#define OFF_BH1 648   // bh1[8]  (bfv @ W1)
#define OFF_BH2 656   // bh2[8]  (bfs @ W1 + b1)
#define CST_N   664

// f32 -> bf16 (RNE), returned in low 16 bits
__device__ __forceinline__ unsigned f2bf(float f) {
    unsigned u = __float_as_uint(f);
    u += 0x7fffu + ((u >> 16) & 1u);
    return u >> 16;
}
__device__ __forceinline__ float bf_lo(unsigned u) { return __uint_as_float(u << 16); }
__device__ __forceinline__ float bf_hi(unsigned u) { return __uint_as_float(u & 0xffff0000u); }

// ---------------------------------------------------------------------------
// K0 (1 block): fold x-encoder into projections, then collapse everything to
// 16-dim operators:
//   Wf[m] = Wx @ Wm (16x64), bf[m] = bx @ Wm + bm       (m: q,k,v,s)
//   M = Wfq Wfk^T; u = Wfk bfq; w = Wfq bfk; c = bfq.bfk
//   R = We Wfq^T; r0 = We bfq
//   Pv = Wfv W1; Ps = Wfs W1; Pe = We W1; bh1 = bfv W1; bh2 = bfs W1 + b1
// ---------------------------------------------------------------------------
__global__ __launch_bounds__(256) void k_fold(
    const float* __restrict__ Wx, const float* __restrict__ bx,
    const float* __restrict__ Wq, const float* __restrict__ bq,
    const float* __restrict__ Wk, const float* __restrict__ bk,
    const float* __restrict__ Wv, const float* __restrict__ bv,
    const float* __restrict__ Ws, const float* __restrict__ bs,
    const float* __restrict__ We, const float* __restrict__ W1,
    const float* __restrict__ b1, float* __restrict__ cst)
{
    __shared__ float sWf[4][16][64];
    __shared__ float sbf[4][64];
    const int t = threadIdx.x;
    const int c = t & 63, m = t >> 6;
    const float* W; const float* b;
    switch (m) {
        case 0:  W = Wq; b = bq; break;
        case 1:  W = Wk; b = bk; break;
        case 2:  W = Wv; b = bv; break;
        default: W = Ws; b = bs; break;
    }
    float acc[16];
#pragma unroll
    for (int i = 0; i < 16; ++i) acc[i] = 0.f;
    float bacc = b[c];
    for (int j = 0; j < 64; ++j) {
        const float wv = W[j * 64 + c];
        bacc += bx[j] * wv;
#pragma unroll
        for (int i = 0; i < 16; ++i) acc[i] += Wx[i * 64 + j] * wv;
    }
#pragma unroll
    for (int i = 0; i < 16; ++i) sWf[m][i][c] = acc[i];
    sbf[m][c] = bacc;
    __syncthreads();

    // M (256 outputs)
    {
        const int i = t >> 4, j = t & 15;
        float s = 0.f;
        for (int cc = 0; cc < 64; ++cc) s += sWf[0][i][cc] * sWf[1][j][cc];
        cst[OFF_M + i * 16 + j] = s;
    }
    if (t < 16) {
        float su = 0.f, sw = 0.f;
        for (int cc = 0; cc < 64; ++cc) {
            su += sWf[1][t][cc] * sbf[0][cc];
            sw += sWf[0][t][cc] * sbf[1][cc];
        }
        cst[OFF_U + t] = su;
        cst[OFF_W + t] = sw;
    }
    if (t == 0) {
        float s = 0.f;
        for (int cc = 0; cc < 64; ++cc) s += sbf[0][cc] * sbf[1][cc];
        cst[OFF_C] = s;
    }
    if (t < 64) {
        const int j = t >> 4, i = t & 15;
        float s = 0.f;
        for (int cc = 0; cc < 64; ++cc) s += We[j * 64 + cc] * sWf[0][i][cc];
        cst[OFF_R + j * 16 + i] = s;
    }
    if (t < 4) {
        float s = 0.f;
        for (int cc = 0; cc < 64; ++cc) s += We[t * 64 + cc] * sbf[0][cc];
        cst[OFF_R0 + t] = s;
    }
    if (t < 128) {
        const int i = t >> 3, j = t & 7;
        float sv = 0.f, ss = 0.f;
        for (int cc = 0; cc < 64; ++cc) {
            const float w1 = W1[cc * 8 + j];
            sv += sWf[2][i][cc] * w1;
            ss += sWf[3][i][cc] * w1;
        }
        cst[OFF_PV + i * 8 + j] = sv;
        cst[OFF_PS + i * 8 + j] = ss;
    }
    if (t < 32) {
        const int mm = t >> 3, j = t & 7;
        float s = 0.f;
        for (int cc = 0; cc < 64; ++cc) s += We[mm * 64 + cc] * W1[cc * 8 + j];
        cst[OFF_PE + mm * 8 + j] = s;
    }
    if (t < 8) {
        float s1 = 0.f, s2 = 0.f;
        for (int cc = 0; cc < 64; ++cc) {
            const float w1 = W1[cc * 8 + t];
            s1 += sbf[2][cc] * w1;
            s2 += sbf[3][cc] * w1;
        }
        cst[OFF_BH1 + t] = s1;
        cst[OFF_BH2 + t] = s2 + b1[t];
    }
}

// ---------------------------------------------------------------------------
// K1: bucket edges by dst. Record: int4 {src, e, bf16x2(A0,A1), bf16x2(A2,A3)}.
// ---------------------------------------------------------------------------
__global__ __launch_bounds__(256) void k_fill(
    const int* __restrict__ src, const int* __restrict__ dst,
    const float4* __restrict__ ea4,
    int* __restrict__ cursor, int4* __restrict__ csr, int E)
{
    const int e = blockIdx.x * 256 + threadIdx.x;
    if (e >= E) return;
    const int s = src[e];
    const int d = dst[e];
    const float4 A = ea4[e];
    const int pos = atomicAdd(&cursor[d], 1);
    if (pos < CAP) {
        int4 ent;
        ent.x = s;
        ent.y = e;
        ent.z = (int)(f2bf(A.x) | (f2bf(A.y) << 16));
        ent.w = (int)(f2bf(A.z) | (f2bf(A.w) << 16));
        csr[(size_t)d * CAP + pos] = ent;
    }
}

// ---------------------------------------------------------------------------
// K2: aggregation entirely in 16-dim space. One node per wave, no LDS/barrier.
// 16 lanes per edge-slot (lane cg holds x-component cg), 4 slots/wave,
// unroll x2 -> 8 edges in flight. Per edge: gather 64B x_s row (L2/L3-hot),
// alpha = y.x_s + cd + A.r via 4-stage butterfly; accumulate T (distributed),
// S, den. Epilogue: tiny folded MLP.
// ---------------------------------------------------------------------------
__global__ __launch_bounds__(256) void k_node_agg(
    const int* __restrict__ degp, const int4* __restrict__ csr,
    const float* __restrict__ x, const float* __restrict__ cst,
    const float* __restrict__ W2, const float* __restrict__ b2,
    float* __restrict__ out, int N)
{
    const int t = threadIdx.x;
    const int l = t & 63;
    const int w = t >> 6;
    const int n = blockIdx.x * 4 + w;
    if (n >= N) return;                  // wave-uniform exit
    const int grp = l >> 4;              // edge slot 0..3
    const int cg  = l & 15;              // x-component index

    const int deg = min(degp[n], CAP);
    const size_t nbase = (size_t)n * CAP;

    const float xd = x[(size_t)n * 16 + cg];

    // y_cg = sum_i x_d[i] * M[i][cg] + u[cg]
    float y = cst[OFF_U + cg];
#pragma unroll
    for (int i = 0; i < 16; ++i)
        y += __shfl(xd, i) * cst[OFF_M + i * 16 + cg];

    // r = R x_d + r0 (replicated), cd = w.x_d + c (replicated)
    float pr0 = cst[OFF_R + 0 * 16 + cg] * xd;
    float pr1 = cst[OFF_R + 1 * 16 + cg] * xd;
    float pr2 = cst[OFF_R + 2 * 16 + cg] * xd;
    float pr3 = cst[OFF_R + 3 * 16 + cg] * xd;
    float pcd = cst[OFF_W + cg] * xd;
#pragma unroll
    for (int d = 1; d < 16; d <<= 1) {
        pr0 += __shfl_xor(pr0, d);
        pr1 += __shfl_xor(pr1, d);
        pr2 += __shfl_xor(pr2, d);
        pr3 += __shfl_xor(pr3, d);
        pcd += __shfl_xor(pcd, d);
    }
    const float r0 = pr0 + cst[OFF_R0 + 0];
    const float r1 = pr1 + cst[OFF_R0 + 1];
    const float r2 = pr2 + cst[OFF_R0 + 2];
    const float r3 = pr3 + cst[OFF_R0 + 3];
    const float cd = pcd + cst[OFF_C];

    float T = 0.f, S0 = 0.f, S1 = 0.f, S2 = 0.f, S3 = 0.f, den = 0.f;

    for (int base = 0; base < deg; base += 8) {
        const int ia = base + grp;
        const int ib = base + 4 + grp;
        const bool va = ia < deg;
        const bool vb = ib < deg;
        const int4 Ea = csr[nbase + (va ? ia : 0)];
        const int4 Eb = csr[nbase + (vb ? ib : 0)];
        const float xsa = x[(size_t)Ea.x * 16 + cg];
        const float xsb = x[(size_t)Eb.x * 16 + cg];
        // slot a
        {
            const float A0 = bf_lo((unsigned)Ea.z), A1 = bf_hi((unsigned)Ea.z);
            const float A2 = bf_lo((unsigned)Ea.w), A3 = bf_hi((unsigned)Ea.w);
            float p = y * xsa;
            p += __shfl_xor(p, 1);
            p += __shfl_xor(p, 2);
            p += __shfl_xor(p, 4);
            p += __shfl_xor(p, 8);
            p += cd + A0 * r0 + A1 * r1 + A2 * r2 + A3 * r3;
            const float a = va ? __expf(p * 0.125f) : 0.f;
            T += a * xsa;
            S0 += a * A0; S1 += a * A1; S2 += a * A2; S3 += a * A3;
            den += a;
        }
        // slot b
        {
            const float A0 = bf_lo((unsigned)Eb.z), A1 = bf_hi((unsigned)Eb.z);
            const float A2 = bf_lo((unsigned)Eb.w), A3 = bf_hi((unsigned)Eb.w);
            float p = y * xsb;
            p += __shfl_xor(p, 1);
            p += __shfl_xor(p, 2);
            p += __shfl_xor(p, 4);
            p += __shfl_xor(p, 8);
            p += cd + A0 * r0 + A1 * r1 + A2 * r2 + A3 * r3;
            const float a = vb ? __expf(p * 0.125f) : 0.f;
            T += a * xsb;
            S0 += a * A0; S1 += a * A1; S2 += a * A2; S3 += a * A3;
            den += a;
        }
    }

    // cross-slot reduce (T distributed by cg; S/den replicated in group)
    T   += __shfl_xor(T, 16);   T   += __shfl_xor(T, 32);
    den += __shfl_xor(den, 16); den += __shfl_xor(den, 32);
    S0  += __shfl_xor(S0, 16);  S0  += __shfl_xor(S0, 32);
    S1  += __shfl_xor(S1, 16);  S1  += __shfl_xor(S1, 32);
    S2  += __shfl_xor(S2, 16);  S2  += __shfl_xor(S2, 32);
    S3  += __shfl_xor(S3, 16);  S3  += __shfl_xor(S3, 32);

    const float inv = 1.f / (den + 1e-16f);
    const float Ti = T * inv;

    // hidden_j = sum_cg [Ti*Pv + xd*Ps] + inv*(S.Pe) + den*inv*bh1 + bh2
    float hp[8];
#pragma unroll
    for (int j = 0; j < 8; ++j)
        hp[j] = Ti * cst[OFF_PV + cg * 8 + j] + xd * cst[OFF_PS + cg * 8 + j];
#pragma unroll
    for (int j = 0; j < 8; ++j) {
        hp[j] += __shfl_xor(hp[j], 1);
        hp[j] += __shfl_xor(hp[j], 2);
        hp[j] += __shfl_xor(hp[j], 4);
        hp[j] += __shfl_xor(hp[j], 8);
    }
    const float dinv = den * inv;
    float val = b2[0];
#pragma unroll
    for (int j = 0; j < 8; ++j) {
        const float hid = hp[j]
            + inv * (S0 * cst[OFF_PE + 0 * 8 + j] + S1 * cst[OFF_PE + 1 * 8 + j]
                   + S2 * cst[OFF_PE + 2 * 8 + j] + S3 * cst[OFF_PE + 3 * 8 + j])
            + dinv * cst[OFF_BH1 + j] + cst[OFF_BH2 + j];
        val += fmaxf(hid, 0.f) * W2[j];
    }

    // scatter per-edge output (csr row L2-hot from the loop above)
    for (int i = l; i < deg; i += 64)
        out[csr[nbase + i].y] = val;
}

// ---------------------------------------------------------------------------
extern "C" void kernel_launch(void* const* d_in, const int* in_sizes, int n_in,
                              void* d_out, int out_size, void* d_ws, size_t ws_size,
                              hipStream_t stream)
{
    const int*   src = (const int*)d_in[0];
    const int*   dst = (const int*)d_in[1];
    const float* x   = (const float*)d_in[3];
    const float* ea  = (const float*)d_in[4];
    const float* Wx  = (const float*)d_in[5];
    const float* bx  = (const float*)d_in[6];
    const float* Wq  = (const float*)d_in[7];
    const float* bq  = (const float*)d_in[8];
    const float* Wk  = (const float*)d_in[9];
    const float* bk  = (const float*)d_in[10];
    const float* Wv  = (const float*)d_in[11];
    const float* bv  = (const float*)d_in[12];
    const float* We  = (const float*)d_in[13];
    const float* Ws  = (const float*)d_in[14];
    const float* bs  = (const float*)d_in[15];
    const float* W1  = (const float*)d_in[16];
    const float* b1  = (const float*)d_in[17];
    const float* W2  = (const float*)d_in[18];
    const float* b2  = (const float*)d_in[19];

    const int E = in_sizes[0];
    const int N = in_sizes[3] / 16;
    float* out = (float*)d_out;

    // workspace layout (~78 MB)
    int4* csr   = (int4*)d_ws;                      // N*CAP records
    int* cursor = (int*)(csr + (size_t)N * CAP);    // N
    float* cst  = (float*)(cursor + N);             // CST_N floats

    hipMemsetAsync(cursor, 0, (size_t)N * sizeof(int), stream);

    k_fold<<<1, 256, 0, stream>>>(Wx, bx, Wq, bq, Wk, bk, Wv, bv, Ws, bs,
                                  We, W1, b1, cst);

    k_fill<<<(E + 255) / 256, 256, 0, stream>>>(
        src, dst, (const float4*)ea, cursor, csr, E);

    k_node_agg<<<(N + 3) / 4, 256, 0, stream>>>(
        cursor, csr, x, cst, W2, b2, out, N);
}